// Round 11
// baseline (301.665 us; speedup 1.0000x reference)
//
#include <hip/hip_runtime.h>
#include <hip/hip_bf16.h>
#include <math.h>

// ---------------------------------------------------------------------------
// ConvFormer: T=8, Ci=1, Co=16, spatial 64^3.
//   k_prep:  k3 MFMA weight frags + k1 MFMA weight frags (f16, row-sloted)
//   k1_qkv:  q/k/v convs as K=27 implicit GEMM on MFMA (pair-packed LDS).
//   k_finstats: sums -> mean/rstd (f32) + f16 (a=rs, b=-m*rs) tables
//   k2_attn: MFMA gating. v2: -log2e folded into Wa3/ba3 -> sigmoid =
//            rcp(1+exp2(s')) (one v_exp + one v_rcp, no per-channel mul).
//   k3_conv: final 16->16 conv, implicit GEMM MFMA. v3: single-barrier —
//            both ci-halves staged upfront via global_load_lds (77.8KB LDS),
//            all 28 weight frags hoisted, 28 uninterrupted MFMA phases.
//   k_finstats; k4_norm: interleaved f16 y -> planar fp32 d_out
// ---------------------------------------------------------------------------

#define V18 (1 << 18)
#define SOFF (3 * (1 << 25))   // float offset of stats region in ws

typedef __attribute__((ext_vector_type(4))) _Float16 f16x4;
typedef __attribute__((ext_vector_type(8))) _Float16 f16x8;
typedef __attribute__((ext_vector_type(4))) float f32x4;

__device__ __forceinline__ float lrelu(float x) { return x > 0.f ? x : 0.2f * x; }

__device__ __forceinline__ f32x4 mfma16(f16x4 a, f16x4 b, f32x4 c) {
  return __builtin_amdgcn_mfma_f32_16x16x16f16(a, b, c, 0, 0, 0);
}

__device__ __forceinline__ f16x4 frag_from_words(const uint* sp, int a) {
  uint2 t;
  t.x = sp[a];
  t.y = sp[a + 2];
  return __builtin_bit_cast(f16x4, t);
}

__device__ __forceinline__ void gload_lds16(const void* g, void* l) {
  __builtin_amdgcn_global_load_lds(
      (const __attribute__((address_space(1))) void*)g,
      (__attribute__((address_space(3))) void*)l, 16, 0, 0);
}

// --------------------------------------------------------------------------
// P layout (f16 units): [0,7168) k3 frags; [7168, 7168+2304) k1 qkv frags.
__global__ void k_prep(const float* __restrict__ Wq, const float* __restrict__ Wk,
                       const float* __restrict__ Wv, const float* __restrict__ Wf,
                       float* __restrict__ P) {
  int tid = threadIdx.x;
  _Float16* wf16 = (_Float16*)P;
  for (int i = tid; i < 7168; i += 256) {
    int h = i / 3584, r = i % 3584, p = r / 256, q_ = r & 255;
    int lane = q_ >> 2, j = q_ & 3;
    int co = lane & 15, kq = lane >> 4;
    int kk = kq * 4 + j, tp = kk >> 3, ci = h * 8 + (kk & 7), tap = p * 2 + tp;
    wf16[i] = (tap < 27) ? (_Float16)Wf[co * 432 + ci * 27 + tap] : (_Float16)0.f;
  }
  _Float16* wqkv = wf16 + 7168;
  for (int i = tid; i < 2304; i += 256) {
    int conv = i / 768, rem = i % 768, m = rem / 256, li = rem & 255;
    int lane = li >> 2, j = li & 3;
    int co = lane & 15, q_ = lane >> 4;
    int r = m * 4 + q_;
    const float* W = conv == 0 ? Wq : conv == 1 ? Wk : Wv;
    float val = 0.f;
    if (r <= 8 && j < 3) val = W[co * 27 + (r / 3) * 9 + (r % 3) * 3 + j];
    wqkv[i] = (_Float16)val;
  }
}

// --------------------------------------------------------------------------
// k1: MFMA conv. tile (z,y,x)=(4,4,64); pair-packed f16 halo tiles (stride
// 72 words); quad-interleaved f16x4 stores; cheap fused stats.
__global__ __launch_bounds__(256) void k1_qkv(
    const float* __restrict__ c, const float* __restrict__ e,
    const float* __restrict__ pos, const _Float16* __restrict__ wqkv,
    const float* __restrict__ bq, const float* __restrict__ bk,
    const float* __restrict__ bv, _Float16* __restrict__ q,
    _Float16* __restrict__ k, _Float16* __restrict__ v,
    float* __restrict__ gstats) {
  __shared__ __align__(16) uint seP[2592];   // 36 rows x 72 words
  __shared__ __align__(16) uint scP[2592];
  __shared__ float red[96];
  const int t = blockIdx.y;
  const int tile = blockIdx.x;               // 256 = 16z * 16y
  const int y0 = (tile & 15) * 4;
  const int z0 = (tile >> 4) * 4;
  const int tid = threadIdx.x;
  const int lane = tid & 63, zw = tid >> 6;
  const int col = lane & 15, cq = lane >> 4;

  if (tid < 96) red[tid] = 0.f;

  _Float16* se16 = (_Float16*)seP;
  _Float16* sc16 = (_Float16*)scP;
  const float* cin = c + t * V18;
  const float* ein = e + t * V18;
  for (int i = tid; i < 2448; i += 256) {
    int rw = i / 68, lx = i % 68;
    int gz = z0 + rw / 6 - 1, gy = y0 + rw % 6 - 1, gx = lx - 1;
    float pe = 0.f, pc = 0.f;
    if (lx < 66 && (unsigned)gz < 64u && (unsigned)gy < 64u && (unsigned)gx < 64u) {
      int gi = (gz << 12) + (gy << 6) + gx;
      float pv = pos[gi];
      pc = cin[gi] + pv;
      pe = ein[gi] + pv;
    }
    const _Float16 he = (_Float16)pe, hc = (_Float16)pc;
    const int wp = rw * 72 + lx;
    se16[2 * wp] = he;
    sc16[2 * wp] = hc;
    if (i) {
      se16[2 * wp - 1] = he;
      sc16[2 * wp - 1] = hc;
    }
  }

  f16x4 wq_[3], wk_[3], wv_[3];
#pragma unroll
  for (int m = 0; m < 3; ++m) {
    wq_[m] = *(const f16x4*)&wqkv[(0 * 3 + m) * 256 + lane * 4];
    wk_[m] = *(const f16x4*)&wqkv[(1 * 3 + m) * 256 + lane * 4];
    wv_[m] = *(const f16x4*)&wqkv[(2 * 3 + m) * 256 + lane * 4];
  }
  const f32x4 bqv = *(const f32x4*)&bq[cq * 4];
  const f32x4 bkv = *(const f32x4*)&bk[cq * 4];
  const f32x4 bvv = *(const f32x4*)&bv[cq * 4];
  int rowoff[3];
#pragma unroll
  for (int m = 0; m < 3; ++m) {
    int r = m * 4 + cq;
    if (r > 8) r = 8;
    rowoff[m] = ((r / 3) * 6 + (r % 3)) * 72;
  }

  f32x4 sq = {0,0,0,0}, sq2 = {0,0,0,0}, sk = {0,0,0,0},
        sk2 = {0,0,0,0}, sv = {0,0,0,0}, sv2 = {0,0,0,0};

  __syncthreads();

#pragma unroll 8
  for (int g = 0; g < 16; ++g) {
    const int gy = g >> 2, xg = g & 3;
    const int base = (zw * 6 + gy) * 72 + xg * 16 + col;
    const int a0 = base + rowoff[0], a1 = base + rowoff[1], a2 = base + rowoff[2];
    f16x4 be0 = frag_from_words(seP, a0);
    f16x4 be1 = frag_from_words(seP, a1);
    f16x4 be2 = frag_from_words(seP, a2);
    f16x4 bc0 = frag_from_words(scP, a0);
    f16x4 bc1 = frag_from_words(scP, a1);
    f16x4 bc2 = frag_from_words(scP, a2);

    f32x4 qa = mfma16(wq_[0], be0, bqv);
    qa = mfma16(wq_[1], be1, qa);
    qa = mfma16(wq_[2], be2, qa);
    f32x4 ka = mfma16(wk_[0], bc0, bkv);
    ka = mfma16(wk_[1], bc1, ka);
    ka = mfma16(wk_[2], bc2, ka);
    f32x4 va = mfma16(wv_[0], bc0, bvv);
    va = mfma16(wv_[1], bc1, va);
    va = mfma16(wv_[2], bc2, va);

    const size_t vox = ((size_t)(z0 + zw) << 12) + ((y0 + gy) << 6) + xg * 16 + col;
    const size_t poff = ((size_t)(t * 4 + cq) << 20) + vox * 4;
    *(f16x4*)&q[poff] = (f16x4){(_Float16)qa[0], (_Float16)qa[1],
                                (_Float16)qa[2], (_Float16)qa[3]};
    *(f16x4*)&k[poff] = (f16x4){(_Float16)ka[0], (_Float16)ka[1],
                                (_Float16)ka[2], (_Float16)ka[3]};
    *(f16x4*)&v[poff] = (f16x4){(_Float16)va[0], (_Float16)va[1],
                                (_Float16)va[2], (_Float16)va[3]};
    sq += qa; sq2 += qa * qa;
    sk += ka; sk2 += ka * ka;
    sv += va; sv2 += va * va;
  }

#pragma unroll
  for (int d = 1; d < 16; d <<= 1) {
#pragma unroll
    for (int j = 0; j < 4; ++j) {
      sq[j] += __shfl_xor(sq[j], d);  sq2[j] += __shfl_xor(sq2[j], d);
      sk[j] += __shfl_xor(sk[j], d);  sk2[j] += __shfl_xor(sk2[j], d);
      sv[j] += __shfl_xor(sv[j], d);  sv2[j] += __shfl_xor(sv2[j], d);
    }
  }
  if (col == 0) {
#pragma unroll
    for (int j = 0; j < 4; ++j) {
      const int co = cq * 4 + j;
      atomicAdd(&red[co * 2], sq[j]);
      atomicAdd(&red[co * 2 + 1], sq2[j]);
      atomicAdd(&red[32 + co * 2], sk[j]);
      atomicAdd(&red[32 + co * 2 + 1], sk2[j]);
      atomicAdd(&red[64 + co * 2], sv[j]);
      atomicAdd(&red[64 + co * 2 + 1], sv2[j]);
    }
  }
  __syncthreads();
  if (tid < 96) {
    const int conv = tid >> 5, rem = tid & 31;
    atomicAdd(&gstats[(conv * 128 + t * 16) * 2 + rem], red[tid]);
  }
}

// --------------------------------------------------------------------------
__global__ void k_finstats(const float* __restrict__ sums, float* __restrict__ mr,
                           _Float16* __restrict__ ah, _Float16* __restrict__ bh,
                           int n, float invn) {
  int i = blockIdx.x * blockDim.x + threadIdx.x;
  if (i >= n) return;
  float m = sums[i * 2] * invn;
  float var = sums[i * 2 + 1] * invn - m * m;
  float rs = rsqrtf(fmaxf(var, 0.f) + 1e-5f);
  mr[i * 2] = m;
  mr[i * 2 + 1] = rs;
  if (ah) {
    ah[i] = (_Float16)rs;
    bh[i] = (_Float16)(-m * rs);
  }
}

// --------------------------------------------------------------------------
// k2 v2: MFMA gating; -log2e folded into Wa3 frag + ba3 C-init so the
// gate MFMA emits s' = -log2e*s; sigmoid = rcp(1+exp2(s')).
__global__ __launch_bounds__(256) void k2_attn(
    const _Float16* __restrict__ q, const _Float16* __restrict__ k,
    const _Float16* __restrict__ v, const float* __restrict__ Wa1,
    const float* __restrict__ Wa2, const float* __restrict__ Wa3,
    const _Float16* __restrict__ ah, const _Float16* __restrict__ bh,
    const float* __restrict__ ba1, const float* __restrict__ ba2,
    const float* __restrict__ ba3, _Float16* __restrict__ u) {
  const int lane = threadIdx.x & 63;
  const int wid = threadIdx.x >> 6;
  const int row = lane & 15;
  const int cq = lane >> 4;
  const int c0 = cq * 4;
  const int vox = (blockIdx.x * 4 + wid) * 16 + row;
  const _Float16 h02 = (_Float16)0.2f;
  const f16x4 hz = {(_Float16)0.f, (_Float16)0.f, (_Float16)0.f, (_Float16)0.f};
  const float nl2e = -1.44269504f;

  f32x4 w1f = *(const f32x4*)&Wa1[row * 16 + c0];
  f32x4 w2f = *(const f32x4*)&Wa2[row * 16 + c0];
  f32x4 w3f = *(const f32x4*)&Wa3[row * 16 + c0];
  f16x4 wa1 = {(_Float16)w1f[0], (_Float16)w1f[1], (_Float16)w1f[2], (_Float16)w1f[3]};
  f16x4 wa2 = {(_Float16)w2f[0], (_Float16)w2f[1], (_Float16)w2f[2], (_Float16)w2f[3]};
  f16x4 wa3 = {(_Float16)(w3f[0] * nl2e), (_Float16)(w3f[1] * nl2e),
               (_Float16)(w3f[2] * nl2e), (_Float16)(w3f[3] * nl2e)};
  f32x4 b1q = *(const f32x4*)&ba1[c0];
  f32x4 b2q = *(const f32x4*)&ba2[c0];
  f32x4 b3f = *(const f32x4*)&ba3[c0];
  f32x4 b3q = {b3f[0] * nl2e, b3f[1] * nl2e, b3f[2] * nl2e, b3f[3] * nl2e};

  f32x4 acc[8];
  f16x4 ahalf[8], qn[8];
#pragma unroll
  for (int t = 0; t < 8; ++t) {
    f16x4 qh = *(const f16x4*)&q[((size_t)(t * 4 + cq) << 20) + (size_t)vox * 4];
    f16x4 a4 = *(const f16x4*)&ah[t * 16 + c0];
    f16x4 b4 = *(const f16x4*)&bh[t * 16 + c0];
    f16x4 x = qh * a4 + b4;
    qn[t] = __builtin_elementwise_max(x, x * h02);
    f32x4 A = mfma16(wa1, qn[t], b1q);
    ahalf[t] = (f16x4){(_Float16)A[0], (_Float16)A[1], (_Float16)A[2], (_Float16)A[3]};
    acc[t] = (f32x4){0.f, 0.f, 0.f, 0.f};
  }
#pragma unroll 1
  for (int j = 0; j < 8; ++j) {
    f16x4 kh = *(const f16x4*)&k[((size_t)(j * 4 + cq) << 20) + (size_t)vox * 4];
    f16x4 vh = *(const f16x4*)&v[((size_t)(j * 4 + cq) << 20) + (size_t)vox * 4];
    f16x4 ka = *(const f16x4*)&ah[128 + j * 16 + c0];
    f16x4 kb = *(const f16x4*)&bh[128 + j * 16 + c0];
    f16x4 va = *(const f16x4*)&ah[256 + j * 16 + c0];
    f16x4 vb = *(const f16x4*)&bh[256 + j * 16 + c0];
    f16x4 xk = kh * ka + kb;
    f16x4 kn = __builtin_elementwise_max(xk, xk * h02);
    f16x4 xv = vh * va + vb;
    f16x4 vn = __builtin_elementwise_max(xv, xv * h02);
    f32x4 vnf = {(float)vn[0], (float)vn[1], (float)vn[2], (float)vn[3]};
    f32x4 B = mfma16(wa2, kn, b2q);
    f16x4 bhh = {(_Float16)B[0], (_Float16)B[1], (_Float16)B[2], (_Float16)B[3]};
#pragma unroll
    for (int i = 0; i < 8; ++i) {
      f16x4 rel = ahalf[i] + bhh;
      f16x4 rh = __builtin_elementwise_max(rel, hz);
      f32x4 s = mfma16(wa3, rh, b3q);    // s = -log2e * gate
#pragma unroll
      for (int ch = 0; ch < 4; ++ch) {
        float sg = __builtin_amdgcn_rcpf(1.f + __builtin_amdgcn_exp2f(s[ch]));
        acc[i][ch] += sg * vnf[ch];
      }
    }
  }
#pragma unroll
  for (int t = 0; t < 8; ++t) {
    f16x4 acch = {(_Float16)acc[t][0], (_Float16)acc[t][1],
                  (_Float16)acc[t][2], (_Float16)acc[t][3]};
    f16x4 uh = acch + qn[t];
    *(f16x4*)&u[((size_t)t << 22) + ((size_t)vox << 4) + c0] = uh;
  }
}

// --------------------------------------------------------------------------
// k3 v3: implicit-GEMM MFMA conv, single-barrier. Both ci-halves staged
// upfront via global_load_lds (4864 slots x 16B = 77.8KB; 19 full passes,
// half boundary 2432 = 38 waves is wave-aligned). All 28 weight frags
// hoisted during staging flight. One barrier, then 28 MFMA phases.
__global__ __launch_bounds__(256, 2) void k3_conv(
    const _Float16* __restrict__ u16, const _Float16* __restrict__ wf16,
    const float* __restrict__ bfv, _Float16* __restrict__ y16,
    float* __restrict__ fsums, const float* __restrict__ zpad) {
  __shared__ __align__(16) _Float16 sx[4864 * 8];  // 77824 B
  __shared__ float red[32];
  const int t = blockIdx.y;
  int tile = blockIdx.x;                    // 256 = 16z * 16y
  tile = (tile & 7) * 32 + (tile >> 3);     // XCD swizzle (bijective)
  const int y0 = (tile & 15) * 4;
  const int z0 = (tile >> 4) * 4;
  const int tid = threadIdx.x;
  const int lane = tid & 63, wv = tid >> 6, zw = wv;

  if (tid < 32) red[tid] = 0.f;

  const int colv = lane & 15;
  const int tp = lane >> 5;
  const int ciq = ((lane >> 4) & 1) * 4;

  const _Float16* ubase = u16 + ((size_t)t << 22);

  // issue ALL staging (both halves); loads stay in flight until the barrier
#pragma unroll 1
  for (int it = 0; it < 19; ++it) {
    const int i = it * 256 + wv * 64 + lane;
    const int h = i >= 2432 ? 1 : 0;
    const int s = i - h * 2432;
    const int rw = s / 66, xs = s % 66;
    const int gz = z0 + rw / 6 - 1, gy = y0 + rw % 6 - 1, gx = xs - 1;
    const bool ok = s < 2376 && (unsigned)gz < 64u && (unsigned)gy < 64u &&
                    (unsigned)gx < 64u;
    const void* src = ok
        ? (const void*)&ubase[(((gz << 12) + (gy << 6) + gx) << 4) + h * 8]
        : (const void*)zpad;
    gload_lds16(src, (void*)&sx[(it * 256 + wv * 64) * 8]);
  }

  // hoist all 28 weight frags + bias (VMEM loads overlap staging flight)
  f16x4 wfr[28];
#pragma unroll
  for (int p = 0; p < 28; ++p)
    wfr[p] = *(const f16x4*)&wf16[p * 256 + lane * 4];
  f32x4 bq = *(const f32x4*)&bfv[(lane >> 4) * 4];
  f32x4 acc[16];
#pragma unroll
  for (int g = 0; g < 16; ++g) acc[g] = bq;

  __syncthreads();                           // single drain: everything landed

#pragma unroll 1
  for (int h = 0; h < 2; ++h) {
#pragma unroll
    for (int p = 0; p < 14; ++p) {
      f16x4 w = wfr[h * 14 + p];
      int tap = p * 2 + tp;
      if (tap > 26) tap = 26;                // pad pair; weights are zero
      const int dz = tap / 9, dy = (tap % 9) / 3, dx = tap % 3;
      const int base_p =
          h * 19456 + (((zw + dz) * 6 + dy) * 66 + colv + dx) * 8 + ciq;
#pragma unroll
      for (int g = 0; g < 16; ++g) {
        f16x4 b = *(const f16x4*)&sx[base_p + ((g >> 2) * 66 + (g & 3) * 16) * 8];
        acc[g] = mfma16(w, b, acc[g]);
      }
    }
  }

  // store y (f16 interleaved) + fused stats
  float s[4] = {0.f, 0.f, 0.f, 0.f}, s2[4] = {0.f, 0.f, 0.f, 0.f};
  _Float16* ybase = y16 + ((size_t)t << 22);
#pragma unroll
  for (int g = 0; g < 16; ++g) {
    const int gvox = ((z0 + zw) << 12) + ((y0 + (g >> 2)) << 6) + (g & 3) * 16 + colv;
    f16x4 o = {(_Float16)acc[g][0], (_Float16)acc[g][1],
               (_Float16)acc[g][2], (_Float16)acc[g][3]};
    *(f16x4*)&ybase[(gvox << 4) + (lane >> 4) * 4] = o;
#pragma unroll
    for (int j = 0; j < 4; ++j) {
      s[j] += acc[g][j];
      s2[j] += acc[g][j] * acc[g][j];
    }
  }
#pragma unroll
  for (int d = 1; d < 16; d <<= 1)
#pragma unroll
    for (int j = 0; j < 4; ++j) {
      s[j] += __shfl_xor(s[j], d);
      s2[j] += __shfl_xor(s2[j], d);
    }
  if ((lane & 15) == 0) {
    const int co0 = (lane >> 4) * 4;
#pragma unroll
    for (int j = 0; j < 4; ++j) {
      atomicAdd(&red[(co0 + j) * 2], s[j]);
      atomicAdd(&red[(co0 + j) * 2 + 1], s2[j]);
    }
  }
  __syncthreads();
  if (tid < 32) atomicAdd(&fsums[t * 32 + tid], red[tid]);
}

// --------------------------------------------------------------------------
// k4: interleaved f16 y -> normalized planar fp32 out.
__global__ __launch_bounds__(256) void k4_norm(const _Float16* __restrict__ y16,
                                               const float* __restrict__ fmr,
                                               float* __restrict__ out) {
  const int t = blockIdx.x >> 8;
  const int vb = (blockIdx.x & 255) << 10;
  const _Float16* yb = y16 + ((size_t)t << 22);
  float* ob = out + ((size_t)t << 22);
  const float* f = fmr + t * 32;
#pragma unroll 1
  for (int it = 0; it < 4; ++it) {
    const int voxl = vb + it * 256 + threadIdx.x;
    f16x8 h0 = *(const f16x8*)&yb[voxl << 4];
    f16x8 h1 = *(const f16x8*)&yb[(voxl << 4) + 8];
#pragma unroll
    for (int co = 0; co < 8; ++co)
      ob[(co << 18) + voxl] = lrelu(((float)h0[co] - f[co * 2]) * f[co * 2 + 1]);
#pragma unroll
    for (int co = 0; co < 8; ++co)
      ob[((co + 8) << 18) + voxl] =
          lrelu(((float)h1[co] - f[(co + 8) * 2]) * f[(co + 8) * 2 + 1]);
  }
}

// --------------------------------------------------------------------------
extern "C" void kernel_launch(void* const* d_in, const int* in_sizes, int n_in,
                              void* d_out, int out_size, void* d_ws, size_t ws_size,
                              hipStream_t stream) {
  const float* c = (const float*)d_in[0];
  const float* e = (const float*)d_in[1];
  const float* pos = (const float*)d_in[2];
  const float* Wq = (const float*)d_in[3];
  const float* bq = (const float*)d_in[4];
  const float* Wk = (const float*)d_in[5];
  const float* bk = (const float*)d_in[6];
  const float* Wv = (const float*)d_in[7];
  const float* bv = (const float*)d_in[8];
  const float* Wa1 = (const float*)d_in[9];
  const float* ba1 = (const float*)d_in[10];
  const float* Wa2 = (const float*)d_in[11];
  const float* ba2 = (const float*)d_in[12];
  const float* Wa3 = (const float*)d_in[13];
  const float* ba3 = (const float*)d_in[14];
  const float* Wf = (const float*)d_in[15];
  const float* bf_ = (const float*)d_in[16];

  float* ws = (float*)d_ws;
  _Float16* q16 = (_Float16*)ws;             // 3 x 2^25 f16 (q,k,v)
  _Float16* k16 = q16 + ((size_t)1 << 25);
  _Float16* v16 = q16 + ((size_t)2 << 25);
  _Float16* y16 = (_Float16*)ws;             // aliases q16 (dead after k2)
  float* stats = ws + SOFF;
  float* fsums = stats + 768;
  float* zpad = stats + 1024;                // 16 zeroed floats
  float* qkvmr = stats + 1040;
  float* fmr = stats + 1808;
  _Float16* ah = (_Float16*)(stats + 2064);  // 384 f16
  _Float16* bh = (_Float16*)(stats + 2256);  // 384 f16
  float* P = stats + 2448;                   // wf16 (7168 f16) + wqkv (2304 f16)
  _Float16* wf16 = (_Float16*)P;
  _Float16* wqkv = wf16 + 7168;
  _Float16* u16 = (_Float16*)d_out;

  hipMemsetAsync(stats, 0, 1040 * sizeof(float), stream);
  hipLaunchKernelGGL(k_prep, dim3(1), dim3(256), 0, stream, Wq, Wk, Wv, Wf, P);
  hipLaunchKernelGGL(k1_qkv, dim3(256, 8), dim3(256), 0, stream,
                     c, e, pos, wqkv, bq, bk, bv, q16, k16, v16, stats);
  hipLaunchKernelGGL(k_finstats, dim3(2), dim3(256), 0, stream,
                     stats, qkvmr, ah, bh, 384, 1.f / 262144.f);
  hipLaunchKernelGGL(k2_attn, dim3(4096), dim3(256), 0, stream,
                     q16, k16, v16, Wa1, Wa2, Wa3, ah, bh, ba1, ba2, ba3, u16);
  hipLaunchKernelGGL(k3_conv, dim3(256, 8), dim3(256), 0, stream,
                     u16, wf16, bf_, y16, fsums, zpad);
  hipLaunchKernelGGL(k_finstats, dim3(1), dim3(256), 0, stream,
                     fsums, fmr, (_Float16*)nullptr, (_Float16*)nullptr,
                     128, 1.f / 262144.f);
  hipLaunchKernelGGL(k4_norm, dim3(2048), dim3(256), 0, stream, y16, fmr,
                     (float*)d_out);
}

// Round 12
// 262.809 us; speedup vs baseline: 1.1479x; 1.1479x over previous
//
#include <hip/hip_runtime.h>
#include <hip/hip_bf16.h>
#include <math.h>

// ---------------------------------------------------------------------------
// ConvFormer: T=8, Ci=1, Co=16, spatial 64^3.
//   k_prep:  k3 K=32 MFMA weight frags + k1 MFMA weight frags (f16)
//   k1_qkv:  q/k/v convs as K=27 implicit GEMM on MFMA (pair-packed LDS).
//   k_finstats: sums -> mean/rstd (f32) + f16 (a=rs, b=-m*rs) tables
//   k2_attn: MFMA gating; -log2e folded into Wa3/ba3; sigmoid=rcp(1+exp2).
//   k3_conv: final 16->16 conv, implicit GEMM. v4 = v2 2-phase structure
//            (global_load_lds staging, hoisted weights, XCD swizzle) +
//            K=32 mfma_f32_16x16x32_f16: lane B-frag = ONE ds_read_b128
//            (8 ci of one tap), 14 MFMAs/g instead of 28.  A packed with
//            the same (quad,slot)->(tap,ci) assignment as B, so the HW's
//            internal slot->k map cancels (layout-safe by construction).
//   k_finstats; k4_norm: interleaved f16 y -> planar fp32 d_out
// ---------------------------------------------------------------------------

#define V18 (1 << 18)
#define SOFF (3 * (1 << 25))   // float offset of stats region in ws

typedef __attribute__((ext_vector_type(4))) _Float16 f16x4;
typedef __attribute__((ext_vector_type(8))) _Float16 f16x8;
typedef __attribute__((ext_vector_type(4))) float f32x4;

__device__ __forceinline__ float lrelu(float x) { return x > 0.f ? x : 0.2f * x; }

__device__ __forceinline__ f32x4 mfma16(f16x4 a, f16x4 b, f32x4 c) {
  return __builtin_amdgcn_mfma_f32_16x16x16f16(a, b, c, 0, 0, 0);
}
__device__ __forceinline__ f32x4 mfma32(f16x8 a, f16x8 b, f32x4 c) {
  return __builtin_amdgcn_mfma_f32_16x16x32_f16(a, b, c, 0, 0, 0);
}

__device__ __forceinline__ f16x4 frag_from_words(const uint* sp, int a) {
  uint2 t;
  t.x = sp[a];
  t.y = sp[a + 2];
  return __builtin_bit_cast(f16x4, t);
}

__device__ __forceinline__ void gload_lds16(const void* g, void* l) {
  __builtin_amdgcn_global_load_lds(
      (const __attribute__((address_space(1))) void*)g,
      (__attribute__((address_space(3))) void*)l, 16, 0, 0);
}

// --------------------------------------------------------------------------
// P layout (f16 units): [0,28672) k3 K=32 frags; [28672,+2304) k1 qkv frags.
__global__ void k_prep(const float* __restrict__ Wq, const float* __restrict__ Wk,
                       const float* __restrict__ Wv, const float* __restrict__ Wf,
                       float* __restrict__ P) {
  int tid = threadIdx.x;
  _Float16* wf16 = (_Float16*)P;
  // k3 v4 frags: wf16[((h*7+tg)*256+lane)*8+j] = Wf[co][ci=h*8+j][tap=tg*4+q]
  // with co=lane&15, q=lane>>4; zero if tap>26.
  for (int i = tid; i < 28672; i += 256) {
    int j = i & 7, lane = (i >> 3) & 255, tg = (i >> 11) % 7, h = i / 14336;
    int co = lane & 15, q_ = lane >> 4;
    int tap = tg * 4 + q_, ci = h * 8 + j;
    wf16[i] = (tap < 27) ? (_Float16)Wf[co * 432 + ci * 27 + tap] : (_Float16)0.f;
  }
  _Float16* wqkv = wf16 + 28672;
  for (int i = tid; i < 2304; i += 256) {
    int conv = i / 768, rem = i % 768, m = rem / 256, li = rem & 255;
    int lane = li >> 2, j = li & 3;
    int co = lane & 15, q_ = lane >> 4;
    int r = m * 4 + q_;
    const float* W = conv == 0 ? Wq : conv == 1 ? Wk : Wv;
    float val = 0.f;
    if (r <= 8 && j < 3) val = W[co * 27 + (r / 3) * 9 + (r % 3) * 3 + j];
    wqkv[i] = (_Float16)val;
  }
}

// --------------------------------------------------------------------------
// k1: MFMA conv. tile (z,y,x)=(4,4,64); pair-packed f16 halo tiles (stride
// 72 words); quad-interleaved f16x4 stores; cheap fused stats.
__global__ __launch_bounds__(256) void k1_qkv(
    const float* __restrict__ c, const float* __restrict__ e,
    const float* __restrict__ pos, const _Float16* __restrict__ wqkv,
    const float* __restrict__ bq, const float* __restrict__ bk,
    const float* __restrict__ bv, _Float16* __restrict__ q,
    _Float16* __restrict__ k, _Float16* __restrict__ v,
    float* __restrict__ gstats) {
  __shared__ __align__(16) uint seP[2592];   // 36 rows x 72 words
  __shared__ __align__(16) uint scP[2592];
  __shared__ float red[96];
  const int t = blockIdx.y;
  const int tile = blockIdx.x;               // 256 = 16z * 16y
  const int y0 = (tile & 15) * 4;
  const int z0 = (tile >> 4) * 4;
  const int tid = threadIdx.x;
  const int lane = tid & 63, zw = tid >> 6;
  const int col = lane & 15, cq = lane >> 4;

  if (tid < 96) red[tid] = 0.f;

  _Float16* se16 = (_Float16*)seP;
  _Float16* sc16 = (_Float16*)scP;
  const float* cin = c + t * V18;
  const float* ein = e + t * V18;
  for (int i = tid; i < 2448; i += 256) {
    int rw = i / 68, lx = i % 68;
    int gz = z0 + rw / 6 - 1, gy = y0 + rw % 6 - 1, gx = lx - 1;
    float pe = 0.f, pc = 0.f;
    if (lx < 66 && (unsigned)gz < 64u && (unsigned)gy < 64u && (unsigned)gx < 64u) {
      int gi = (gz << 12) + (gy << 6) + gx;
      float pv = pos[gi];
      pc = cin[gi] + pv;
      pe = ein[gi] + pv;
    }
    const _Float16 he = (_Float16)pe, hc = (_Float16)pc;
    const int wp = rw * 72 + lx;
    se16[2 * wp] = he;
    sc16[2 * wp] = hc;
    if (i) {
      se16[2 * wp - 1] = he;
      sc16[2 * wp - 1] = hc;
    }
  }

  f16x4 wq_[3], wk_[3], wv_[3];
#pragma unroll
  for (int m = 0; m < 3; ++m) {
    wq_[m] = *(const f16x4*)&wqkv[(0 * 3 + m) * 256 + lane * 4];
    wk_[m] = *(const f16x4*)&wqkv[(1 * 3 + m) * 256 + lane * 4];
    wv_[m] = *(const f16x4*)&wqkv[(2 * 3 + m) * 256 + lane * 4];
  }
  const f32x4 bqv = *(const f32x4*)&bq[cq * 4];
  const f32x4 bkv = *(const f32x4*)&bk[cq * 4];
  const f32x4 bvv = *(const f32x4*)&bv[cq * 4];
  int rowoff[3];
#pragma unroll
  for (int m = 0; m < 3; ++m) {
    int r = m * 4 + cq;
    if (r > 8) r = 8;
    rowoff[m] = ((r / 3) * 6 + (r % 3)) * 72;
  }

  f32x4 sq = {0,0,0,0}, sq2 = {0,0,0,0}, sk = {0,0,0,0},
        sk2 = {0,0,0,0}, sv = {0,0,0,0}, sv2 = {0,0,0,0};

  __syncthreads();

#pragma unroll 8
  for (int g = 0; g < 16; ++g) {
    const int gy = g >> 2, xg = g & 3;
    const int base = (zw * 6 + gy) * 72 + xg * 16 + col;
    const int a0 = base + rowoff[0], a1 = base + rowoff[1], a2 = base + rowoff[2];
    f16x4 be0 = frag_from_words(seP, a0);
    f16x4 be1 = frag_from_words(seP, a1);
    f16x4 be2 = frag_from_words(seP, a2);
    f16x4 bc0 = frag_from_words(scP, a0);
    f16x4 bc1 = frag_from_words(scP, a1);
    f16x4 bc2 = frag_from_words(scP, a2);

    f32x4 qa = mfma16(wq_[0], be0, bqv);
    qa = mfma16(wq_[1], be1, qa);
    qa = mfma16(wq_[2], be2, qa);
    f32x4 ka = mfma16(wk_[0], bc0, bkv);
    ka = mfma16(wk_[1], bc1, ka);
    ka = mfma16(wk_[2], bc2, ka);
    f32x4 va = mfma16(wv_[0], bc0, bvv);
    va = mfma16(wv_[1], bc1, va);
    va = mfma16(wv_[2], bc2, va);

    const size_t vox = ((size_t)(z0 + zw) << 12) + ((y0 + gy) << 6) + xg * 16 + col;
    const size_t poff = ((size_t)(t * 4 + cq) << 20) + vox * 4;
    *(f16x4*)&q[poff] = (f16x4){(_Float16)qa[0], (_Float16)qa[1],
                                (_Float16)qa[2], (_Float16)qa[3]};
    *(f16x4*)&k[poff] = (f16x4){(_Float16)ka[0], (_Float16)ka[1],
                                (_Float16)ka[2], (_Float16)ka[3]};
    *(f16x4*)&v[poff] = (f16x4){(_Float16)va[0], (_Float16)va[1],
                                (_Float16)va[2], (_Float16)va[3]};
    sq += qa; sq2 += qa * qa;
    sk += ka; sk2 += ka * ka;
    sv += va; sv2 += va * va;
  }

#pragma unroll
  for (int d = 1; d < 16; d <<= 1) {
#pragma unroll
    for (int j = 0; j < 4; ++j) {
      sq[j] += __shfl_xor(sq[j], d);  sq2[j] += __shfl_xor(sq2[j], d);
      sk[j] += __shfl_xor(sk[j], d);  sk2[j] += __shfl_xor(sk2[j], d);
      sv[j] += __shfl_xor(sv[j], d);  sv2[j] += __shfl_xor(sv2[j], d);
    }
  }
  if (col == 0) {
#pragma unroll
    for (int j = 0; j < 4; ++j) {
      const int co = cq * 4 + j;
      atomicAdd(&red[co * 2], sq[j]);
      atomicAdd(&red[co * 2 + 1], sq2[j]);
      atomicAdd(&red[32 + co * 2], sk[j]);
      atomicAdd(&red[32 + co * 2 + 1], sk2[j]);
      atomicAdd(&red[64 + co * 2], sv[j]);
      atomicAdd(&red[64 + co * 2 + 1], sv2[j]);
    }
  }
  __syncthreads();
  if (tid < 96) {
    const int conv = tid >> 5, rem = tid & 31;
    atomicAdd(&gstats[(conv * 128 + t * 16) * 2 + rem], red[tid]);
  }
}

// --------------------------------------------------------------------------
__global__ void k_finstats(const float* __restrict__ sums, float* __restrict__ mr,
                           _Float16* __restrict__ ah, _Float16* __restrict__ bh,
                           int n, float invn) {
  int i = blockIdx.x * blockDim.x + threadIdx.x;
  if (i >= n) return;
  float m = sums[i * 2] * invn;
  float var = sums[i * 2 + 1] * invn - m * m;
  float rs = rsqrtf(fmaxf(var, 0.f) + 1e-5f);
  mr[i * 2] = m;
  mr[i * 2 + 1] = rs;
  if (ah) {
    ah[i] = (_Float16)rs;
    bh[i] = (_Float16)(-m * rs);
  }
}

// --------------------------------------------------------------------------
// k2 v2: MFMA gating; -log2e folded into Wa3 frag + ba3 C-init so the
// gate MFMA emits s' = -log2e*s; sigmoid = rcp(1+exp2(s')).
__global__ __launch_bounds__(256) void k2_attn(
    const _Float16* __restrict__ q, const _Float16* __restrict__ k,
    const _Float16* __restrict__ v, const float* __restrict__ Wa1,
    const float* __restrict__ Wa2, const float* __restrict__ Wa3,
    const _Float16* __restrict__ ah, const _Float16* __restrict__ bh,
    const float* __restrict__ ba1, const float* __restrict__ ba2,
    const float* __restrict__ ba3, _Float16* __restrict__ u) {
  const int lane = threadIdx.x & 63;
  const int wid = threadIdx.x >> 6;
  const int row = lane & 15;
  const int cq = lane >> 4;
  const int c0 = cq * 4;
  const int vox = (blockIdx.x * 4 + wid) * 16 + row;
  const _Float16 h02 = (_Float16)0.2f;
  const f16x4 hz = {(_Float16)0.f, (_Float16)0.f, (_Float16)0.f, (_Float16)0.f};
  const float nl2e = -1.44269504f;

  f32x4 w1f = *(const f32x4*)&Wa1[row * 16 + c0];
  f32x4 w2f = *(const f32x4*)&Wa2[row * 16 + c0];
  f32x4 w3f = *(const f32x4*)&Wa3[row * 16 + c0];
  f16x4 wa1 = {(_Float16)w1f[0], (_Float16)w1f[1], (_Float16)w1f[2], (_Float16)w1f[3]};
  f16x4 wa2 = {(_Float16)w2f[0], (_Float16)w2f[1], (_Float16)w2f[2], (_Float16)w2f[3]};
  f16x4 wa3 = {(_Float16)(w3f[0] * nl2e), (_Float16)(w3f[1] * nl2e),
               (_Float16)(w3f[2] * nl2e), (_Float16)(w3f[3] * nl2e)};
  f32x4 b1q = *(const f32x4*)&ba1[c0];
  f32x4 b2q = *(const f32x4*)&ba2[c0];
  f32x4 b3f = *(const f32x4*)&ba3[c0];
  f32x4 b3q = {b3f[0] * nl2e, b3f[1] * nl2e, b3f[2] * nl2e, b3f[3] * nl2e};

  f32x4 acc[8];
  f16x4 ahalf[8], qn[8];
#pragma unroll
  for (int t = 0; t < 8; ++t) {
    f16x4 qh = *(const f16x4*)&q[((size_t)(t * 4 + cq) << 20) + (size_t)vox * 4];
    f16x4 a4 = *(const f16x4*)&ah[t * 16 + c0];
    f16x4 b4 = *(const f16x4*)&bh[t * 16 + c0];
    f16x4 x = qh * a4 + b4;
    qn[t] = __builtin_elementwise_max(x, x * h02);
    f32x4 A = mfma16(wa1, qn[t], b1q);
    ahalf[t] = (f16x4){(_Float16)A[0], (_Float16)A[1], (_Float16)A[2], (_Float16)A[3]};
    acc[t] = (f32x4){0.f, 0.f, 0.f, 0.f};
  }
#pragma unroll 1
  for (int j = 0; j < 8; ++j) {
    f16x4 kh = *(const f16x4*)&k[((size_t)(j * 4 + cq) << 20) + (size_t)vox * 4];
    f16x4 vh = *(const f16x4*)&v[((size_t)(j * 4 + cq) << 20) + (size_t)vox * 4];
    f16x4 ka = *(const f16x4*)&ah[128 + j * 16 + c0];
    f16x4 kb = *(const f16x4*)&bh[128 + j * 16 + c0];
    f16x4 va = *(const f16x4*)&ah[256 + j * 16 + c0];
    f16x4 vb = *(const f16x4*)&bh[256 + j * 16 + c0];
    f16x4 xk = kh * ka + kb;
    f16x4 kn = __builtin_elementwise_max(xk, xk * h02);
    f16x4 xv = vh * va + vb;
    f16x4 vn = __builtin_elementwise_max(xv, xv * h02);
    f32x4 vnf = {(float)vn[0], (float)vn[1], (float)vn[2], (float)vn[3]};
    f32x4 B = mfma16(wa2, kn, b2q);
    f16x4 bhh = {(_Float16)B[0], (_Float16)B[1], (_Float16)B[2], (_Float16)B[3]};
#pragma unroll
    for (int i = 0; i < 8; ++i) {
      f16x4 rel = ahalf[i] + bhh;
      f16x4 rh = __builtin_elementwise_max(rel, hz);
      f32x4 s = mfma16(wa3, rh, b3q);    // s = -log2e * gate
#pragma unroll
      for (int ch = 0; ch < 4; ++ch) {
        float sg = __builtin_amdgcn_rcpf(1.f + __builtin_amdgcn_exp2f(s[ch]));
        acc[i][ch] += sg * vnf[ch];
      }
    }
  }
#pragma unroll
  for (int t = 0; t < 8; ++t) {
    f16x4 acch = {(_Float16)acc[t][0], (_Float16)acc[t][1],
                  (_Float16)acc[t][2], (_Float16)acc[t][3]};
    f16x4 uh = acch + qn[t];
    *(f16x4*)&u[((size_t)t << 22) + ((size_t)vox << 4) + c0] = uh;
  }
}

// --------------------------------------------------------------------------
// k3 v4: implicit-GEMM conv on K=32 MFMA. Tile (4,4,64), 4 waves (z-slice),
// 16 groups/wave, ci-split 2 stages of 8 (38.9KB LDS, v2 structure).
// Lane tap = tg*4 + (lane>>4); B-frag = one ds_read_b128 (8 ci of that
// tap at the lane's voxel). 14 MFMAs + 14 b128 per g total (both halves).
__global__ __launch_bounds__(256) void k3_conv(
    const _Float16* __restrict__ u16, const _Float16* __restrict__ wf16,
    const float* __restrict__ bfv, _Float16* __restrict__ y16,
    float* __restrict__ fsums, const float* __restrict__ zpad) {
  __shared__ __align__(16) _Float16 sx[2432 * 8];  // 38912 B
  __shared__ float red[32];
  const int t = blockIdx.y;
  int tile = blockIdx.x;                    // 256 = 16z * 16y
  tile = (tile & 7) * 32 + (tile >> 3);     // XCD swizzle (bijective)
  const int y0 = (tile & 15) * 4;
  const int z0 = (tile >> 4) * 4;
  const int tid = threadIdx.x;
  const int lane = tid & 63, wv = tid >> 6, zw = wv;

  if (tid < 32) red[tid] = 0.f;

  const int colv = lane & 15;
  const int tq = lane >> 4;                 // tap-in-group AND output row quad

  // per-lane tap slot offsets for the 7 tap-groups
  int offt[7];
#pragma unroll
  for (int tg = 0; tg < 7; ++tg) {
    int tap = tg * 4 + tq;
    if (tap > 26) tap = 26;                 // pad tap; weights are zero
    const int dz = tap / 9, dy = (tap % 9) / 3, dx = tap % 3;
    offt[tg] = ((zw + dz) * 6 + dy) * 66 + dx;
  }

  f32x4 bq = *(const f32x4*)&bfv[tq * 4];
  f32x4 acc[16];
#pragma unroll
  for (int g = 0; g < 16; ++g) acc[g] = bq;

  const _Float16* ubase = u16 + ((size_t)t << 22);

#pragma unroll 1
  for (int h = 0; h < 2; ++h) {
    if (h) __syncthreads();                 // all waves done reading h=0 tile

    // hoist this half's weight frags to registers (overlaps staging)
    f16x8 wfr[7];
#pragma unroll
    for (int tg = 0; tg < 7; ++tg)
      wfr[tg] = *(const f16x8*)&wf16[((h * 7 + tg) * 256 + lane) * 8];

    // stage 2376 x 16B via global_load_lds; 9 full passes + 2-wave tail
#pragma unroll 1
    for (int it = 0; it < 9; ++it) {
      const int i = it * 256 + tid;
      const int rw = i / 66, xs = i % 66;
      const int gz = z0 + rw / 6 - 1, gy = y0 + rw % 6 - 1, gx = xs - 1;
      const bool ok = (unsigned)gz < 64u && (unsigned)gy < 64u && (unsigned)gx < 64u;
      const void* src = ok
          ? (const void*)&ubase[(((gz << 12) + (gy << 6) + gx) << 4) + h * 8]
          : (const void*)zpad;
      gload_lds16(src, (void*)&sx[(it * 256 + wv * 64) * 8]);
    }
    if (tid < 128) {                        // slots 2304..2431
      const int i = 2304 + tid;
      const int rw = i / 66, xs = i % 66;
      const int gz = z0 + rw / 6 - 1, gy = y0 + rw % 6 - 1, gx = xs - 1;
      const bool ok = i < 2376 && (unsigned)gz < 64u && (unsigned)gy < 64u &&
                      (unsigned)gx < 64u;
      const void* src = ok
          ? (const void*)&ubase[(((gz << 12) + (gy << 6) + gx) << 4) + h * 8]
          : (const void*)zpad;
      gload_lds16(src, (void*)&sx[(2304 + (tid >> 6) * 64) * 8]);
    }
    __syncthreads();                        // drains vmcnt (loads landed)

#pragma unroll
    for (int tg = 0; tg < 7; ++tg) {
      const f16x8 w = wfr[tg];
      const int bofft = offt[tg];
#pragma unroll
      for (int g = 0; g < 16; ++g) {
        f16x8 b = *(const f16x8*)
            &sx[(bofft + (g >> 2) * 66 + (g & 3) * 16 + colv) * 8];
        acc[g] = mfma32(w, b, acc[g]);
      }
    }
  }

  // store y (f16 interleaved) + fused stats
  float s[4] = {0.f, 0.f, 0.f, 0.f}, s2[4] = {0.f, 0.f, 0.f, 0.f};
  _Float16* ybase = y16 + ((size_t)t << 22);
#pragma unroll
  for (int g = 0; g < 16; ++g) {
    const int gvox = ((z0 + zw) << 12) + ((y0 + (g >> 2)) << 6) + (g & 3) * 16 + colv;
    f16x4 o = {(_Float16)acc[g][0], (_Float16)acc[g][1],
               (_Float16)acc[g][2], (_Float16)acc[g][3]};
    *(f16x4*)&ybase[(gvox << 4) + tq * 4] = o;
#pragma unroll
    for (int j = 0; j < 4; ++j) {
      s[j] += acc[g][j];
      s2[j] += acc[g][j] * acc[g][j];
    }
  }
#pragma unroll
  for (int d = 1; d < 16; d <<= 1)
#pragma unroll
    for (int j = 0; j < 4; ++j) {
      s[j] += __shfl_xor(s[j], d);
      s2[j] += __shfl_xor(s2[j], d);
    }
  if ((lane & 15) == 0) {
    const int co0 = tq * 4;
#pragma unroll
    for (int j = 0; j < 4; ++j) {
      atomicAdd(&red[(co0 + j) * 2], s[j]);
      atomicAdd(&red[(co0 + j) * 2 + 1], s2[j]);
    }
  }
  __syncthreads();
  if (tid < 32) atomicAdd(&fsums[t * 32 + tid], red[tid]);
}

// --------------------------------------------------------------------------
// k4: interleaved f16 y -> normalized planar fp32 out.
__global__ __launch_bounds__(256) void k4_norm(const _Float16* __restrict__ y16,
                                               const float* __restrict__ fmr,
                                               float* __restrict__ out) {
  const int t = blockIdx.x >> 8;
  const int vb = (blockIdx.x & 255) << 10;
  const _Float16* yb = y16 + ((size_t)t << 22);
  float* ob = out + ((size_t)t << 22);
  const float* f = fmr + t * 32;
#pragma unroll 1
  for (int it = 0; it < 4; ++it) {
    const int voxl = vb + it * 256 + threadIdx.x;
    f16x8 h0 = *(const f16x8*)&yb[voxl << 4];
    f16x8 h1 = *(const f16x8*)&yb[(voxl << 4) + 8];
#pragma unroll
    for (int co = 0; co < 8; ++co)
      ob[(co << 18) + voxl] = lrelu(((float)h0[co] - f[co * 2]) * f[co * 2 + 1]);
#pragma unroll
    for (int co = 0; co < 8; ++co)
      ob[((co + 8) << 18) + voxl] =
          lrelu(((float)h1[co] - f[(co + 8) * 2]) * f[(co + 8) * 2 + 1]);
  }
}

// --------------------------------------------------------------------------
extern "C" void kernel_launch(void* const* d_in, const int* in_sizes, int n_in,
                              void* d_out, int out_size, void* d_ws, size_t ws_size,
                              hipStream_t stream) {
  const float* c = (const float*)d_in[0];
  const float* e = (const float*)d_in[1];
  const float* pos = (const float*)d_in[2];
  const float* Wq = (const float*)d_in[3];
  const float* bq = (const float*)d_in[4];
  const float* Wk = (const float*)d_in[5];
  const float* bk = (const float*)d_in[6];
  const float* Wv = (const float*)d_in[7];
  const float* bv = (const float*)d_in[8];
  const float* Wa1 = (const float*)d_in[9];
  const float* ba1 = (const float*)d_in[10];
  const float* Wa2 = (const float*)d_in[11];
  const float* ba2 = (const float*)d_in[12];
  const float* Wa3 = (const float*)d_in[13];
  const float* ba3 = (const float*)d_in[14];
  const float* Wf = (const float*)d_in[15];
  const float* bf_ = (const float*)d_in[16];

  float* ws = (float*)d_ws;
  _Float16* q16 = (_Float16*)ws;             // 3 x 2^25 f16 (q,k,v)
  _Float16* k16 = q16 + ((size_t)1 << 25);
  _Float16* v16 = q16 + ((size_t)2 << 25);
  _Float16* y16 = (_Float16*)ws;             // aliases q16 (dead after k2)
  float* stats = ws + SOFF;
  float* fsums = stats + 768;
  float* zpad = stats + 1024;                // 16 zeroed floats
  float* qkvmr = stats + 1040;
  float* fmr = stats + 1808;
  _Float16* ah = (_Float16*)(stats + 2064);  // 384 f16
  _Float16* bh = (_Float16*)(stats + 2256);  // 384 f16
  float* P = stats + 2448;                   // wf16 (28672 f16) + wqkv (2304 f16)
  _Float16* wf16 = (_Float16*)P;
  _Float16* wqkv = wf16 + 28672;
  _Float16* u16 = (_Float16*)d_out;

  hipMemsetAsync(stats, 0, 1040 * sizeof(float), stream);
  hipLaunchKernelGGL(k_prep, dim3(1), dim3(256), 0, stream, Wq, Wk, Wv, Wf, P);
  hipLaunchKernelGGL(k1_qkv, dim3(256, 8), dim3(256), 0, stream,
                     c, e, pos, wqkv, bq, bk, bv, q16, k16, v16, stats);
  hipLaunchKernelGGL(k_finstats, dim3(2), dim3(256), 0, stream,
                     stats, qkvmr, ah, bh, 384, 1.f / 262144.f);
  hipLaunchKernelGGL(k2_attn, dim3(4096), dim3(256), 0, stream,
                     q16, k16, v16, Wa1, Wa2, Wa3, ah, bh, ba1, ba2, ba3, u16);
  hipLaunchKernelGGL(k3_conv, dim3(256, 8), dim3(256), 0, stream,
                     u16, wf16, bf_, y16, fsums, zpad);
  hipLaunchKernelGGL(k_finstats, dim3(1), dim3(256), 0, stream,
                     fsums, fmr, (_Float16*)nullptr, (_Float16*)nullptr,
                     128, 1.f / 262144.f);
  hipLaunchKernelGGL(k4_norm, dim3(2048), dim3(256), 0, stream, y16, fmr,
                     (float*)d_out);
}